// Round 1
// baseline (14953.943 us; speedup 1.0000x reference)
//
#include <hip/hip_runtime.h>
#include <math.h>

#define BB 32
#define TT 128
#define EE 256
#define HH 1024
#define VOCAB 32000
#define FOURH 4096

#define SPLITK1 4
#define KC1 320        // 1280 / 4
#define SPLITK2 8
#define KC2 256        // 2048 / 8

__device__ __forceinline__ float sigf(float x) {
  return 1.0f / (1.0f + expf(-x));
}

// ---------------------------------------------------------------------------
// Layer-1 z partial GEMM: z[b][col] += sum_{k in chunk} in[b][k] * W1[k][col]
// in[b][k] = k<256 ? emb[idx[b*T+t]][k] : h1[b][k-256]
// grid: (32 colblocks of 128, SPLITK1), block 256
// ---------------------------------------------------------------------------
__global__ __launch_bounds__(256) void lstm_z1(
    const int* __restrict__ idx, const float* __restrict__ emb,
    const float* __restrict__ h1, const float* __restrict__ W1,
    float* __restrict__ zp, int t)
{
  __shared__ float a_sm[KC1][36];   // [k][b], pad 36 keeps 16B align + banks spread
  const int tid = threadIdx.x;
  const int sp  = blockIdx.y;
  const int k0  = sp * KC1;

  for (int i = tid; i < BB * KC1; i += 256) {
    int b = i / KC1;
    int k = i - b * KC1;
    int gk = k0 + k;
    float v;
    if (gk < EE) v = emb[(size_t)idx[b * TT + t] * EE + gk];
    else         v = h1[b * HH + gk - EE];
    a_sm[k][b] = v;
  }
  __syncthreads();

  const int cg = tid & 31;
  const int bg = tid >> 5;
  const int col = blockIdx.x * 128 + cg * 4;
  const float* Wp = W1 + (size_t)k0 * FOURH + col;

  float acc[4][4];
  #pragma unroll
  for (int i = 0; i < 4; ++i)
    #pragma unroll
    for (int j = 0; j < 4; ++j) acc[i][j] = 0.0f;

  #pragma unroll 4
  for (int k = 0; k < KC1; ++k) {
    float4 w = *(const float4*)Wp; Wp += FOURH;
    float4 a = *(const float4*)&a_sm[k][bg * 4];
    float av[4] = {a.x, a.y, a.z, a.w};
    float wv[4] = {w.x, w.y, w.z, w.w};
    #pragma unroll
    for (int i = 0; i < 4; ++i)
      #pragma unroll
      for (int j = 0; j < 4; ++j)
        acc[i][j] += av[i] * wv[j];
  }

  float* zb = zp + ((size_t)sp * BB + bg * 4) * FOURH + col;
  #pragma unroll
  for (int i = 0; i < 4; ++i) {
    float4 o = {acc[i][0], acc[i][1], acc[i][2], acc[i][3]};
    *(float4*)&zb[(size_t)i * FOURH] = o;
  }
}

// ---------------------------------------------------------------------------
// Layer-2 z partial GEMM: in[b][k] = k<1024 ? h1[b][k] : h2[b][k-1024]
// grid: (32, SPLITK2), block 256
// ---------------------------------------------------------------------------
__global__ __launch_bounds__(256) void lstm_z2(
    const float* __restrict__ h1, const float* __restrict__ h2,
    const float* __restrict__ W2, float* __restrict__ zp)
{
  __shared__ float a_sm[KC2][36];
  const int tid = threadIdx.x;
  const int sp  = blockIdx.y;
  const int k0  = sp * KC2;

  for (int i = tid; i < BB * KC2; i += 256) {
    int b = i >> 8;          // KC2 = 256
    int k = i & 255;
    int gk = k0 + k;
    float v;
    if (gk < HH) v = h1[b * HH + gk];
    else         v = h2[b * HH + gk - HH];
    a_sm[k][b] = v;
  }
  __syncthreads();

  const int cg = tid & 31;
  const int bg = tid >> 5;
  const int col = blockIdx.x * 128 + cg * 4;
  const float* Wp = W2 + (size_t)k0 * FOURH + col;

  float acc[4][4];
  #pragma unroll
  for (int i = 0; i < 4; ++i)
    #pragma unroll
    for (int j = 0; j < 4; ++j) acc[i][j] = 0.0f;

  #pragma unroll 4
  for (int k = 0; k < KC2; ++k) {
    float4 w = *(const float4*)Wp; Wp += FOURH;
    float4 a = *(const float4*)&a_sm[k][bg * 4];
    float av[4] = {a.x, a.y, a.z, a.w};
    float wv[4] = {w.x, w.y, w.z, w.w};
    #pragma unroll
    for (int i = 0; i < 4; ++i)
      #pragma unroll
      for (int j = 0; j < 4; ++j)
        acc[i][j] += av[i] * wv[j];
  }

  float* zb = zp + ((size_t)sp * BB + bg * 4) * FOURH + col;
  #pragma unroll
  for (int i = 0; i < 4; ++i) {
    float4 o = {acc[i][0], acc[i][1], acc[i][2], acc[i][3]};
    *(float4*)&zb[(size_t)i * FOURH] = o;
  }
}

// ---------------------------------------------------------------------------
// Gate fusion: reduce split-K partials + bias, apply LSTM gates, update c,h.
// Optionally store h into hs (outputs, row = b*T + t). grid 128 x 256.
// ---------------------------------------------------------------------------
__global__ __launch_bounds__(256) void lstm_gates(
    const float* __restrict__ zp, const float* __restrict__ bias,
    float* __restrict__ c, float* __restrict__ h,
    float* __restrict__ hs, int splitk, int t)
{
  const int id = blockIdx.x * 256 + threadIdx.x;   // 0 .. 32767
  const int b = id >> 10;
  const int u = id & 1023;

  float zi = bias[u];
  float zj = bias[HH + u];
  float zf = bias[2 * HH + u];
  float zo = bias[3 * HH + u];
  for (int sp = 0; sp < splitk; ++sp) {
    const float* z = zp + ((size_t)sp * BB + b) * FOURH;
    zi += z[u];
    zj += z[HH + u];
    zf += z[2 * HH + u];
    zo += z[3 * HH + u];
  }
  float cv = c[id];
  float cn = cv * sigf(zf) + sigf(zi) * tanhf(zj);
  float hn = tanhf(cn) * sigf(zo);
  c[id] = cn;
  h[id] = hn;
  if (hs) hs[((size_t)b * TT + t) * HH + u] = hn;
}

// ---------------------------------------------------------------------------
// Logits GEMM: C[r][v] = sum_k A[r][k] * Bw[v][k] + bias[v]
// A: [4096,1024], Bw: [32000,1024], C: [4096,32000]
// BM=BN=128, BK=16, 8x8 thread tile, block 256. grid (250, 32).
// ---------------------------------------------------------------------------
__global__ __launch_bounds__(256) void logits_gemm(
    const float* __restrict__ A, const float* __restrict__ Bw,
    const float* __restrict__ bias, float* __restrict__ C)
{
  __shared__ float As[16][132];
  __shared__ float Bs[16][132];

  const int tid = threadIdx.x;
  const int tx = tid & 15;    // n-group: 8 cols
  const int ty = tid >> 4;    // m-group: 8 rows
  const int row0 = blockIdx.y * 128;
  const int col0 = blockIdx.x * 128;

  float acc[8][8];
  #pragma unroll
  for (int i = 0; i < 8; ++i)
    #pragma unroll
    for (int j = 0; j < 8; ++j) acc[i][j] = 0.0f;

  for (int k0 = 0; k0 < 1024; k0 += 16) {
    #pragma unroll
    for (int s = 0; s < 2; ++s) {
      int f = tid + s * 256;          // 0..511
      int r = f >> 2;                 // 0..127
      int kq = (f & 3) * 4;
      float4 va = *(const float4*)&A[(size_t)(row0 + r) * 1024 + k0 + kq];
      As[kq + 0][r] = va.x; As[kq + 1][r] = va.y;
      As[kq + 2][r] = va.z; As[kq + 3][r] = va.w;
      float4 vb = *(const float4*)&Bw[(size_t)(col0 + r) * 1024 + k0 + kq];
      Bs[kq + 0][r] = vb.x; Bs[kq + 1][r] = vb.y;
      Bs[kq + 2][r] = vb.z; Bs[kq + 3][r] = vb.w;
    }
    __syncthreads();

    #pragma unroll
    for (int kk = 0; kk < 16; ++kk) {
      float4 a0 = *(const float4*)&As[kk][ty * 8];
      float4 a1 = *(const float4*)&As[kk][ty * 8 + 4];
      float4 b0 = *(const float4*)&Bs[kk][tx * 8];
      float4 b1 = *(const float4*)&Bs[kk][tx * 8 + 4];
      float ar[8] = {a0.x, a0.y, a0.z, a0.w, a1.x, a1.y, a1.z, a1.w};
      float br[8] = {b0.x, b0.y, b0.z, b0.w, b1.x, b1.y, b1.z, b1.w};
      #pragma unroll
      for (int i = 0; i < 8; ++i)
        #pragma unroll
        for (int j = 0; j < 8; ++j)
          acc[i][j] += ar[i] * br[j];
    }
    __syncthreads();
  }

  float bi0[8];
  #pragma unroll
  for (int j = 0; j < 8; ++j) bi0[j] = bias[col0 + tx * 8 + j];

  #pragma unroll
  for (int i = 0; i < 8; ++i) {
    size_t roff = (size_t)(row0 + ty * 8 + i) * VOCAB + col0 + tx * 8;
    float4 o0 = {acc[i][0] + bi0[0], acc[i][1] + bi0[1],
                 acc[i][2] + bi0[2], acc[i][3] + bi0[3]};
    float4 o1 = {acc[i][4] + bi0[4], acc[i][5] + bi0[5],
                 acc[i][6] + bi0[6], acc[i][7] + bi0[7]};
    *(float4*)&C[roff]     = o0;
    *(float4*)&C[roff + 4] = o1;
  }
}

// ---------------------------------------------------------------------------
extern "C" void kernel_launch(void* const* d_in, const int* in_sizes, int n_in,
                              void* d_out, int out_size, void* d_ws, size_t ws_size,
                              hipStream_t stream) {
  const int*   idx = (const int*)  d_in[0];
  const float* emb = (const float*)d_in[1];
  const float* W1  = (const float*)d_in[2];
  const float* b1  = (const float*)d_in[3];
  const float* W2  = (const float*)d_in[4];
  const float* b2  = (const float*)d_in[5];
  const float* sw  = (const float*)d_in[6];
  const float* sb  = (const float*)d_in[7];
  float* out = (float*)d_out;

  float* ws = (float*)d_ws;
  float* c1  = ws;                       // 32768
  float* h1  = c1 + BB * HH;             // 32768
  float* c2  = h1 + BB * HH;             // 32768
  float* h2  = c2 + BB * HH;             // 32768
  float* zp1 = h2 + BB * HH;             // SPLITK1*32*4096 = 524288
  float* zp2 = zp1 + (size_t)SPLITK1 * BB * FOURH;  // 1048576
  float* hs  = zp2 + (size_t)SPLITK2 * BB * FOURH;  // 4194304

  // zero initial LSTM state (ws is poisoned 0xAA before every launch)
  hipMemsetAsync(c1, 0, (size_t)4 * BB * HH * sizeof(float), stream);

  for (int t = 0; t < TT; ++t) {
    lstm_z1<<<dim3(32, SPLITK1), 256, 0, stream>>>(idx, emb, h1, W1, zp1, t);
    lstm_gates<<<128, 256, 0, stream>>>(zp1, b1, c1, h1, nullptr, SPLITK1, t);
    lstm_z2<<<dim3(32, SPLITK2), 256, 0, stream>>>(h1, h2, W2, zp2);
    lstm_gates<<<128, 256, 0, stream>>>(zp2, b2, c2, h2, hs, SPLITK2, t);
  }

  logits_gemm<<<dim3(VOCAB / 128, (BB * TT) / 128), 256, 0, stream>>>(hs, sw, sb, out);
}